// Round 24
// baseline (51.404 us; speedup 1.0000x reference)
//
#include <hip/hip_runtime.h>
#include <hip/hip_bf16.h>
#include <stdint.h>

// Problem constants
#define B_ 16
#define C_ 256
#define H_ 64
#define W_ 64
#define WP 66                   // padded width: w' = w+1, border cols 0 and 65 zero
#define HP 66                   // padded height: h' = h+1, border rows 0 and 65 zero
#define ROWB (WP * 128)         // bytes per padded row of fp4 signs = 8448
#define STAGEB (3 * ROWB + 32)  // 3 rows staged + pad = 25376

typedef __attribute__((ext_vector_type(4))) float f32x4;
typedef __attribute__((ext_vector_type(4))) int int4v;
typedef __attribute__((ext_vector_type(8))) int int8v;

typedef const __attribute__((address_space(1))) uint32_t* gptr_t;
typedef __attribute__((address_space(3))) uint32_t* lptr_t;

__device__ __forceinline__ void gl_lds16(const void* g, void* l) {
  __builtin_amdgcn_global_load_lds((gptr_t)g, (lptr_t)l, 16, 0, 0);
}

// fp4 e2m1 signs: +1 = 0x2, -1 = 0xA, 0 = 0x0 (exact)
__device__ __forceinline__ uint8_t sgn4(float v) {
  return v > 0.f ? (uint8_t)0x2 : (v < 0.f ? (uint8_t)0xA : (uint8_t)0);
}

// fp4 uses only the low 4 regs of the 8-reg f8f6f4 operand; upper 4 undef.
#define EXT8(v4) __builtin_shufflevector((v4), (v4), 0, 1, 2, 3, -1, -1, -1, -1)

// ---------- kernel A (MERGED): prep_w (blocks 0..255) + binarize (blocks 256..4351) ----------
// (byte-identical to round 22 — 16x16x128 wtb layout restored)
__global__ void prep_and_binarize(const float* __restrict__ w,
                                  float* __restrict__ scale,
                                  uint8_t* __restrict__ wtb,
                                  const float* __restrict__ x,
                                  const float* __restrict__ bias,
                                  uint8_t* __restrict__ a_p) {
  int tid = threadIdx.x;
  if (blockIdx.x < 256) {  // ---- prep_w ----
    int o = blockIdx.x, c = tid;
    const float* wo = w + (size_t)o * 2304 + (size_t)c * 9;  // w[o][c][kh][kw]
    float v[9];
    float s = 0.f;
#pragma unroll
    for (int t = 0; t < 9; ++t) { v[t] = wo[t]; s += fabsf(v[t]); }
    __shared__ float red[256];
    __shared__ uint8_t sg[9][256];
    red[c] = s;
#pragma unroll
    for (int t = 0; t < 9; ++t) sg[t][c] = sgn4(v[t]);
    __syncthreads();
    for (int st = 128; st > 0; st >>= 1) {
      if (c < st) red[c] += red[c + st];
      __syncthreads();
    }
    if (c == 0) scale[o] = red[0] / 2304.0f;
    if (c < 128) {  // thread c packs channels 2c, 2c+1 into one byte
      int k = c;
      int ot = o >> 6, mi = (o >> 4) & 3, lm = o & 15;
      int kh = k >> 6, lk = (k >> 4) & 3, jb = k & 15;
      int l = lk * 16 + lm;
#pragma unroll
      for (int t = 0; t < 9; ++t) {
        uint8_t byte = (uint8_t)(sg[t][2 * k] | (sg[t][2 * k + 1] << 4));
        wtb[((((size_t)t * 4 + ot) * 2 + kh) * 4 + mi) * 1024 + l * 16 + jb] = byte;
      }
    }
    return;
  }
  // ---- binarize ----
  int id = blockIdx.x - 256;
  int bh = id >> 2, b = bh >> 6, h = bh & 63, c0 = (id & 3) * 64;
  __shared__ uint8_t lt[64][72];  // [w][ci], sgn4 value in low nibble
#pragma unroll
  for (int p = 0; p < 4; ++p) {
    int ci = p * 16 + (tid >> 4), w4 = (tid & 15) * 4;
    f32x4 v = *(const f32x4*)(x + (((size_t)(b * C_ + c0 + ci) * H_ + h) * W_ + w4));
    float bb = bias[c0 + ci];
#pragma unroll
    for (int k = 0; k < 4; ++k) lt[w4 + k][ci] = sgn4(v[k] + bb);
  }
  __syncthreads();
  size_t rowbase = (size_t)(b * HP + h + 1) * ROWB;
#pragma unroll
  for (int r = 0; r < 2; ++r) {
    int u = r * 256 + tid;             // 0..511 ; this y-block: 64 px x 8 u32
    int w_ = u >> 3, q = u & 7;        // q-th u32 (8 channels) of pixel w
    uint32_t val = 0;
#pragma unroll
    for (int e = 0; e < 8; ++e)
      val |= (uint32_t)(lt[w_][q * 8 + e] & 15) << (4 * e);
    int wp = w_ + 1;
    int ch = (c0 + q * 8) >> 5;
    int pos = wp * 128 + (((ch ^ wp) & 7) << 4) + (q & 3) * 4;
    *(uint32_t*)(a_p + rowbase + pos) = val;
  }
  // zero border pixel blocks; for edge h, zero the padded border rows.
  if ((id & 3) == 0) {
    if (tid < 32) *(uint32_t*)(a_p + rowbase + tid * 4) = 0;
    else if (tid < 64) *(uint32_t*)(a_p + rowbase + 65 * 128 + (tid - 32) * 4) = 0;
  }
  if (h == 0) {  // zero row h'=0 (quarter per y-block)
    uint32_t* zr = (uint32_t*)(a_p + (size_t)b * HP * ROWB) + (id & 3) * 528;
    for (int k = tid; k < 528; k += 256) zr[k] = 0;
  } else if (h == 63) {  // zero row h'=65
    uint32_t* zr = (uint32_t*)(a_p + ((size_t)b * HP + 65) * ROWB) + (id & 3) * 528;
    for (int k = tid; k < 528; k += 256) zr[k] = 0;
  }
}

// ---------- kernel B: binary conv, MX-fp4 16x16x128, 512-thread blocks ----------
// Round-24: 8 waves/block, wave owns 32 channels (wm = wv*32). Live regs ~84
// (32 acc + 32 frag + addr) -> __launch_bounds__(512,4): 16 waves/CU,
// 2 blocks resident, 1024 blocks = 4/CU = 2 EXACT rounds (kills the r5
// packing tail without r6's LDS/wave regression). All 8 waves broadcast-read
// the same LDS B staging (bf is wv-independent). Loop schedule = r19/r22.
#define LOADW(dst, t, kh) {                                                       \
  const uint8_t* wb_ = wtb + (((((size_t)(t) * 4 + (wv >> 1)) * 2 + (kh)) * 4 +   \
                               (wv & 1) * 2) * 1024) + l * 16;                    \
  dst[0] = *(const int4v*)(wb_);                                                  \
  dst[1] = *(const int4v*)(wb_ + 1024); }

#define LOADB(dst, d, dxi, kh) {                                                  \
  int ch_ = (kh) * 4 + lk;                                                        \
  _Pragma("unroll") for (int ni = 0; ni < 4; ++ni) {                              \
    int wp_ = ni * 16 + lm + (dxi);                                               \
    dst[ni] = *(const int4v*)(smem + (d) * ROWB + wp_ * 128 +                     \
                              (((ch_ ^ wp_) & 7) << 4)); } }

#define MFMA_BURST(wreg)                                                          \
  __builtin_amdgcn_s_setprio(1);                                                  \
  _Pragma("unroll") for (int mi = 0; mi < 2; ++mi)                                \
    _Pragma("unroll") for (int ni = 0; ni < 4; ++ni)                              \
      acc[mi][ni] = __builtin_amdgcn_mfma_scale_f32_16x16x128_f8f6f4(             \
          EXT8(wreg[mi]), EXT8(bf[ni]), acc[mi][ni], 4, 4, 0, 127, 0, 127);       \
  __builtin_amdgcn_s_setprio(0);

__global__ __launch_bounds__(512, 4) void bconv(
    const uint8_t* __restrict__ a_p, const uint8_t* __restrict__ wtb,
    const float* __restrict__ scale, const float* __restrict__ x,
    const float* __restrict__ pb0, const float* __restrict__ alpha,
    const float* __restrict__ pb1, float* __restrict__ out) {
  __shared__ __attribute__((aligned(16))) uint8_t smem[STAGEB];
  // XCD-aware bijective swizzle: 1024 blocks, 8 XCDs, 128 contiguous per XCD
  int bh = (blockIdx.x & 7) * 128 + (blockIdx.x >> 3);
  int b = bh >> 6, h = bh & 63;
  int tid = threadIdx.x, l = tid & 63, wv = tid >> 6;
  int lm = l & 15, lk = l >> 4;
  int wm = wv * 32;               // wave owns channels [wv*32, wv*32+32)

  // stage 3 contiguous padded rows (h', h'+1, h'+2) = input rows h-1,h,h+1
  const uint8_t* src = a_p + (size_t)(b * HP + h) * ROWB;
#pragma unroll
  for (int it = 0; it < 3; ++it)
    gl_lds16(src + (size_t)(it * 512 + tid) * 16, smem + it * 8192 + wv * 1024);
  if (tid < 48) gl_lds16(src + 24576 + (size_t)tid * 16, smem + 24576);

  f32x4 acc[2][4];
#pragma unroll
  for (int i = 0; i < 2; ++i)
#pragma unroll
    for (int j = 0; j < 4; ++j) acc[i][j] = (f32x4){0.f, 0.f, 0.f, 0.f};

  asm volatile("s_waitcnt vmcnt(0)" ::: "memory");
  __syncthreads();

  int4v wA[2], wB[2], bf[4];
  LOADW(wA, 0, 0)
#pragma unroll 1
  for (int t = 0; t < 9; ++t) {      // tap loop NOT unrolled: fences code motion
    int d = t / 3, dxi = t - d * 3;
    // step kh=0: prefetch (t,1) into wB, B JIT, burst with wA
    LOADW(wB, t, 1)
    LOADB(bf, d, dxi, 0)
    MFMA_BURST(wA)
    // step kh=1: prefetch (t+1,0) into wA, B JIT, burst with wB
    if (t < 8) { LOADW(wA, t + 1, 0) }
    LOADB(bf, d, dxi, 1)
    MFMA_BURST(wB)
  }

  // epilogue: conv*scale + pb0 -> PReLU -> + pb1 + x (residual)
  size_t xb = (size_t)b * C_ * H_ * W_ + (size_t)h * W_;
#pragma unroll
  for (int mi = 0; mi < 2; ++mi) {
#pragma unroll
    for (int j = 0; j < 4; ++j) {
      int o = wm + mi * 16 + lk * 4 + j;  // C/D row = (lane>>4)*4 + reg
      float sc = scale[o], b0 = pb0[o], al = alpha[o], b1 = pb1[o];
      size_t rowo = xb + (size_t)o * (H_ * W_);
#pragma unroll
      for (int ni = 0; ni < 4; ++ni) {
        int wcol = ni * 16 + lm;          // C/D col = lane&15
        float v = acc[mi][ni][j] * sc + b0;
        v = v >= 0.f ? v : al * v;
        v = v + b1 + x[rowo + wcol];
        out[rowo + wcol] = v;
      }
    }
  }
}

extern "C" void kernel_launch(void* const* d_in, const int* in_sizes, int n_in,
                              void* d_out, int out_size, void* d_ws, size_t ws_size,
                              hipStream_t stream) {
  const float* x     = (const float*)d_in[0];
  const float* m0b   = (const float*)d_in[1];
  const float* w     = (const float*)d_in[2];
  const float* pb0   = (const float*)d_in[3];
  const float* alpha = (const float*)d_in[4];
  const float* pb1   = (const float*)d_in[5];
  float* out = (float*)d_out;

  // ws: [0,4KB) scale | [4096, +294912+pad) wtb fp4 | a_p padded 16*66*8448 = 8.9MB
  float* scale = (float*)d_ws;
  uint8_t* wtb = (uint8_t*)d_ws + 4096;
  uint8_t* a_p = (uint8_t*)d_ws + 4096 + (size_t)9 * 4 * 2 * 4 * 1024 + 1024;

  hipLaunchKernelGGL(prep_and_binarize, dim3(256 + B_ * H_ * 4), dim3(256), 0,
                     stream, w, scale, wtb, x, m0b, a_p);
  hipLaunchKernelGGL(bconv, dim3(B_ * H_), dim3(512), 0, stream,
                     a_p, wtb, scale, x, pb0, alpha, pb1, out);
}

// Round 25
// 50.472 us; speedup vs baseline: 1.0185x; 1.0185x over previous
//
#include <hip/hip_runtime.h>
#include <hip/hip_bf16.h>
#include <stdint.h>

// Problem constants
#define B_ 16
#define C_ 256
#define H_ 64
#define W_ 64
#define WP 66                   // padded width: w' = w+1, border cols 0 and 65 zero
#define HP 66                   // padded height: h' = h+1, border rows 0 and 65 zero
#define ROWB (WP * 128)         // bytes per padded row of fp4 signs = 8448
#define STAGEB (3 * ROWB + 32)  // 3 rows staged + pad = 25376

typedef __attribute__((ext_vector_type(4))) float f32x4;
typedef __attribute__((ext_vector_type(4))) int int4v;
typedef __attribute__((ext_vector_type(8))) int int8v;

typedef const __attribute__((address_space(1))) uint32_t* gptr_t;
typedef __attribute__((address_space(3))) uint32_t* lptr_t;

__device__ __forceinline__ void gl_lds16(const void* g, void* l) {
  __builtin_amdgcn_global_load_lds((gptr_t)g, (lptr_t)l, 16, 0, 0);
}

// fp4 e2m1 signs: +1 = 0x2, -1 = 0xA, 0 = 0x0 (exact)
__device__ __forceinline__ uint8_t sgn4(float v) {
  return v > 0.f ? (uint8_t)0x2 : (v < 0.f ? (uint8_t)0xA : (uint8_t)0);
}

// fp4 uses only the low 4 regs of the 8-reg f8f6f4 operand; upper 4 undef.
#define EXT8(v4) __builtin_shufflevector((v4), (v4), 0, 1, 2, 3, -1, -1, -1, -1)

// ---------- kernel A (MERGED): prep_w (blocks 0..255) + binarize (blocks 256..4351) ----------
// prep_w: wtb[t][ot][kh][mi][lane][16B]; o = ot*64+mi*16+(l&15),
//         c = kh*128+(l>>4)*32+j. binarize: a_p row b*66+(h+1), 66 blocks of
//         128B = 8 chunks of 16B, chunk=(c>>5), stored chunk ^= (w'&7).
__global__ void prep_and_binarize(const float* __restrict__ w,
                                  float* __restrict__ scale,
                                  uint8_t* __restrict__ wtb,
                                  const float* __restrict__ x,
                                  const float* __restrict__ bias,
                                  uint8_t* __restrict__ a_p) {
  int tid = threadIdx.x;
  if (blockIdx.x < 256) {  // ---- prep_w ----
    int o = blockIdx.x, c = tid;
    const float* wo = w + (size_t)o * 2304 + (size_t)c * 9;  // w[o][c][kh][kw]
    float v[9];
    float s = 0.f;
#pragma unroll
    for (int t = 0; t < 9; ++t) { v[t] = wo[t]; s += fabsf(v[t]); }
    __shared__ float red[256];
    __shared__ uint8_t sg[9][256];
    red[c] = s;
#pragma unroll
    for (int t = 0; t < 9; ++t) sg[t][c] = sgn4(v[t]);
    __syncthreads();
    for (int st = 128; st > 0; st >>= 1) {
      if (c < st) red[c] += red[c + st];
      __syncthreads();
    }
    if (c == 0) scale[o] = red[0] / 2304.0f;
    if (c < 128) {  // thread c packs channels 2c, 2c+1 into one byte
      int k = c;
      int ot = o >> 6, mi = (o >> 4) & 3, lm = o & 15;
      int kh = k >> 6, lk = (k >> 4) & 3, jb = k & 15;
      int l = lk * 16 + lm;
#pragma unroll
      for (int t = 0; t < 9; ++t) {
        uint8_t byte = (uint8_t)(sg[t][2 * k] | (sg[t][2 * k + 1] << 4));
        wtb[((((size_t)t * 4 + ot) * 2 + kh) * 4 + mi) * 1024 + l * 16 + jb] = byte;
      }
    }
    return;
  }
  // ---- binarize ----
  int id = blockIdx.x - 256;
  int bh = id >> 2, b = bh >> 6, h = bh & 63, c0 = (id & 3) * 64;
  __shared__ uint8_t lt[64][72];  // [w][ci], sgn4 value in low nibble
#pragma unroll
  for (int p = 0; p < 4; ++p) {
    int ci = p * 16 + (tid >> 4), w4 = (tid & 15) * 4;
    f32x4 v = *(const f32x4*)(x + (((size_t)(b * C_ + c0 + ci) * H_ + h) * W_ + w4));
    float bb = bias[c0 + ci];
#pragma unroll
    for (int k = 0; k < 4; ++k) lt[w4 + k][ci] = sgn4(v[k] + bb);
  }
  __syncthreads();
  size_t rowbase = (size_t)(b * HP + h + 1) * ROWB;
#pragma unroll
  for (int r = 0; r < 2; ++r) {
    int u = r * 256 + tid;             // 0..511 ; this y-block: 64 px x 8 u32
    int w_ = u >> 3, q = u & 7;        // q-th u32 (8 channels) of pixel w
    uint32_t val = 0;
#pragma unroll
    for (int e = 0; e < 8; ++e)
      val |= (uint32_t)(lt[w_][q * 8 + e] & 15) << (4 * e);
    int wp = w_ + 1;
    int ch = (c0 + q * 8) >> 5;
    int pos = wp * 128 + (((ch ^ wp) & 7) << 4) + (q & 3) * 4;
    *(uint32_t*)(a_p + rowbase + pos) = val;
  }
  // zero border pixel blocks; for edge h, zero the padded border rows.
  if ((id & 3) == 0) {
    if (tid < 32) *(uint32_t*)(a_p + rowbase + tid * 4) = 0;
    else if (tid < 64) *(uint32_t*)(a_p + rowbase + 65 * 128 + (tid - 32) * 4) = 0;
  }
  if (h == 0) {  // zero row h'=0 (quarter per y-block)
    uint32_t* zr = (uint32_t*)(a_p + (size_t)b * HP * ROWB) + (id & 3) * 528;
    for (int k = tid; k < 528; k += 256) zr[k] = 0;
  } else if (h == 63) {  // zero row h'=65
    uint32_t* zr = (uint32_t*)(a_p + ((size_t)b * HP + 65) * ROWB) + (id & 3) * 528;
    for (int k = tid; k < 528; k += 256) zr[k] = 0;
  }
}

// ---------- kernel B: binary conv, MX-fp4 MFMA, int4v frags + W ping-pong ----------
// r22 verified best (50.4 us total; 183 -> 50.4 cumulative, 3.6x).
// W prefetched one step ahead; B JIT from swizzled LDS; 3 blocks/CU.
// Falsified alternatives: deeper pipelining (r20), fused binarize (r21),
// 32x32 shape (r23), 512-thread blocks (r24) — all flat or worse.
#define LOADW(dst, t, kh) {                                                       \
  const uint8_t* wb_ = wtb + ((((size_t)(t) * 4 + wv) * 2 + (kh)) * 4) * 1024 + l * 16; \
  _Pragma("unroll") for (int mi = 0; mi < 4; ++mi)                                \
      dst[mi] = *(const int4v*)(wb_ + mi * 1024); }

#define LOADB(dst, d, dxi, kh) {                                                  \
  int ch_ = (kh) * 4 + lk;                                                        \
  _Pragma("unroll") for (int ni = 0; ni < 4; ++ni) {                              \
    int wp_ = ni * 16 + lm + (dxi);                                               \
    dst[ni] = *(const int4v*)(smem + (d) * ROWB + wp_ * 128 +                     \
                              (((ch_ ^ wp_) & 7) << 4)); } }

#define MFMA_BURST(wreg)                                                          \
  __builtin_amdgcn_s_setprio(1);                                                  \
  _Pragma("unroll") for (int mi = 0; mi < 4; ++mi)                                \
    _Pragma("unroll") for (int ni = 0; ni < 4; ++ni)                              \
      acc[mi][ni] = __builtin_amdgcn_mfma_scale_f32_16x16x128_f8f6f4(             \
          EXT8(wreg[mi]), EXT8(bf[ni]), acc[mi][ni], 4, 4, 0, 127, 0, 127);       \
  __builtin_amdgcn_s_setprio(0);

__global__ __launch_bounds__(256, 3) void bconv(
    const uint8_t* __restrict__ a_p, const uint8_t* __restrict__ wtb,
    const float* __restrict__ scale, const float* __restrict__ x,
    const float* __restrict__ pb0, const float* __restrict__ alpha,
    const float* __restrict__ pb1, float* __restrict__ out) {
  __shared__ __attribute__((aligned(16))) uint8_t smem[STAGEB];
  // XCD-aware bijective swizzle: 1024 blocks, 8 XCDs, 128 contiguous per XCD
  int bh = (blockIdx.x & 7) * 128 + (blockIdx.x >> 3);
  int b = bh >> 6, h = bh & 63;
  int tid = threadIdx.x, l = tid & 63, wv = tid >> 6;
  int lm = l & 15, lk = l >> 4;
  int wm = wv * 64;

  // stage 3 contiguous padded rows (h', h'+1, h'+2) = input rows h-1,h,h+1
  const uint8_t* src = a_p + (size_t)(b * HP + h) * ROWB;
#pragma unroll
  for (int it = 0; it < 6; ++it)
    gl_lds16(src + (size_t)(it * 256 + tid) * 16, smem + it * 4096 + wv * 1024);
  if (tid < 48) gl_lds16(src + 24576 + (size_t)tid * 16, smem + 24576);

  f32x4 acc[4][4];
#pragma unroll
  for (int i = 0; i < 4; ++i)
#pragma unroll
    for (int j = 0; j < 4; ++j) acc[i][j] = (f32x4){0.f, 0.f, 0.f, 0.f};

  asm volatile("s_waitcnt vmcnt(0)" ::: "memory");
  __syncthreads();

  int4v wA[4], wB[4], bf[4];
  LOADW(wA, 0, 0)
#pragma unroll 1
  for (int t = 0; t < 9; ++t) {      // tap loop NOT unrolled: fences code motion
    int d = t / 3, dxi = t - d * 3;
    // step kh=0: prefetch (t,1) into wB, B JIT, burst with wA
    LOADW(wB, t, 1)
    LOADB(bf, d, dxi, 0)
    MFMA_BURST(wA)
    // step kh=1: prefetch (t+1,0) into wA, B JIT, burst with wB
    if (t < 8) { LOADW(wA, t + 1, 0) }
    LOADB(bf, d, dxi, 1)
    MFMA_BURST(wB)
  }

  // epilogue: conv*scale + pb0 -> PReLU -> + pb1 + x (residual)
  size_t xb = (size_t)b * C_ * H_ * W_ + (size_t)h * W_;
#pragma unroll
  for (int mi = 0; mi < 4; ++mi) {
#pragma unroll
    for (int j = 0; j < 4; ++j) {
      int o = wm + mi * 16 + lk * 4 + j;  // C/D row = (lane>>4)*4 + reg
      float sc = scale[o], b0 = pb0[o], al = alpha[o], b1 = pb1[o];
      size_t rowo = xb + (size_t)o * (H_ * W_);
#pragma unroll
      for (int ni = 0; ni < 4; ++ni) {
        int wcol = ni * 16 + lm;          // C/D col = lane&15
        float v = acc[mi][ni][j] * sc + b0;
        v = v >= 0.f ? v : al * v;
        v = v + b1 + x[rowo + wcol];
        out[rowo + wcol] = v;
      }
    }
  }
}

extern "C" void kernel_launch(void* const* d_in, const int* in_sizes, int n_in,
                              void* d_out, int out_size, void* d_ws, size_t ws_size,
                              hipStream_t stream) {
  const float* x     = (const float*)d_in[0];
  const float* m0b   = (const float*)d_in[1];
  const float* w     = (const float*)d_in[2];
  const float* pb0   = (const float*)d_in[3];
  const float* alpha = (const float*)d_in[4];
  const float* pb1   = (const float*)d_in[5];
  float* out = (float*)d_out;

  // ws: [0,4KB) scale | [4096, +294912+pad) wtb fp4 | a_p padded 16*66*8448 = 8.9MB
  float* scale = (float*)d_ws;
  uint8_t* wtb = (uint8_t*)d_ws + 4096;
  uint8_t* a_p = (uint8_t*)d_ws + 4096 + (size_t)9 * 4 * 2 * 4 * 1024 + 1024;

  hipLaunchKernelGGL(prep_and_binarize, dim3(256 + B_ * H_ * 4), dim3(256), 0,
                     stream, w, scale, wtb, x, m0b, a_p);
  hipLaunchKernelGGL(bconv, dim3(B_ * H_), dim3(256), 0, stream,
                     a_p, wtb, scale, x, pb0, alpha, pb1, out);
}

// Round 26
// 48.639 us; speedup vs baseline: 1.0569x; 1.0377x over previous
//
#include <hip/hip_runtime.h>
#include <hip/hip_bf16.h>
#include <stdint.h>

// Problem constants
#define B_ 16
#define C_ 256
#define H_ 64
#define W_ 64
#define WP 66                   // padded width: w' = w+1, border cols 0 and 65 zero
#define HP 66                   // padded height: h' = h+1, border rows 0 and 65 zero
#define ROWB (WP * 128)         // bytes per padded row of fp4 signs = 8448
#define STAGEB (3 * ROWB + 32)  // 3 rows staged + pad = 25376

typedef __attribute__((ext_vector_type(4))) float f32x4;
typedef __attribute__((ext_vector_type(4))) int int4v;

typedef const __attribute__((address_space(1))) uint32_t* gptr_t;
typedef __attribute__((address_space(3))) uint32_t* lptr_t;

__device__ __forceinline__ void gl_lds16(const void* g, void* l) {
  __builtin_amdgcn_global_load_lds((gptr_t)g, (lptr_t)l, 16, 0, 0);
}

// fp4 e2m1 signs: +1 = 0x2, -1 = 0xA, 0 = 0x0 (exact)
__device__ __forceinline__ uint8_t sgn4(float v) {
  return v > 0.f ? (uint8_t)0x2 : (v < 0.f ? (uint8_t)0xA : (uint8_t)0);
}

// fp4 uses only the low 4 regs of the 8-reg f8f6f4 operand; upper 4 undef.
#define EXT8(v4) __builtin_shufflevector((v4), (v4), 0, 1, 2, 3, -1, -1, -1, -1)

// ---------- kernel A (MERGED): prep_w (blocks 0..255) + binarize (blocks 256..4351) ----------
// (byte-identical to round 22/25)
__global__ void prep_and_binarize(const float* __restrict__ w,
                                  float* __restrict__ scale,
                                  uint8_t* __restrict__ wtb,
                                  const float* __restrict__ x,
                                  const float* __restrict__ bias,
                                  uint8_t* __restrict__ a_p) {
  int tid = threadIdx.x;
  if (blockIdx.x < 256) {  // ---- prep_w ----
    int o = blockIdx.x, c = tid;
    const float* wo = w + (size_t)o * 2304 + (size_t)c * 9;  // w[o][c][kh][kw]
    float v[9];
    float s = 0.f;
#pragma unroll
    for (int t = 0; t < 9; ++t) { v[t] = wo[t]; s += fabsf(v[t]); }
    __shared__ float red[256];
    __shared__ uint8_t sg[9][256];
    red[c] = s;
#pragma unroll
    for (int t = 0; t < 9; ++t) sg[t][c] = sgn4(v[t]);
    __syncthreads();
    for (int st = 128; st > 0; st >>= 1) {
      if (c < st) red[c] += red[c + st];
      __syncthreads();
    }
    if (c == 0) scale[o] = red[0] / 2304.0f;
    if (c < 128) {  // thread c packs channels 2c, 2c+1 into one byte
      int k = c;
      int ot = o >> 6, mi = (o >> 4) & 3, lm = o & 15;
      int kh = k >> 6, lk = (k >> 4) & 3, jb = k & 15;
      int l = lk * 16 + lm;
#pragma unroll
      for (int t = 0; t < 9; ++t) {
        uint8_t byte = (uint8_t)(sg[t][2 * k] | (sg[t][2 * k + 1] << 4));
        wtb[((((size_t)t * 4 + ot) * 2 + kh) * 4 + mi) * 1024 + l * 16 + jb] = byte;
      }
    }
    return;
  }
  // ---- binarize ----
  int id = blockIdx.x - 256;
  int bh = id >> 2, b = bh >> 6, h = bh & 63, c0 = (id & 3) * 64;
  __shared__ uint8_t lt[64][72];  // [w][ci], sgn4 value in low nibble
#pragma unroll
  for (int p = 0; p < 4; ++p) {
    int ci = p * 16 + (tid >> 4), w4 = (tid & 15) * 4;
    f32x4 v = *(const f32x4*)(x + (((size_t)(b * C_ + c0 + ci) * H_ + h) * W_ + w4));
    float bb = bias[c0 + ci];
#pragma unroll
    for (int k = 0; k < 4; ++k) lt[w4 + k][ci] = sgn4(v[k] + bb);
  }
  __syncthreads();
  size_t rowbase = (size_t)(b * HP + h + 1) * ROWB;
#pragma unroll
  for (int r = 0; r < 2; ++r) {
    int u = r * 256 + tid;             // 0..511 ; this y-block: 64 px x 8 u32
    int w_ = u >> 3, q = u & 7;        // q-th u32 (8 channels) of pixel w
    uint32_t val = 0;
#pragma unroll
    for (int e = 0; e < 8; ++e)
      val |= (uint32_t)(lt[w_][q * 8 + e] & 15) << (4 * e);
    int wp = w_ + 1;
    int ch = (c0 + q * 8) >> 5;
    int pos = wp * 128 + (((ch ^ wp) & 7) << 4) + (q & 3) * 4;
    *(uint32_t*)(a_p + rowbase + pos) = val;
  }
  // zero border pixel blocks; for edge h, zero the padded border rows.
  if ((id & 3) == 0) {
    if (tid < 32) *(uint32_t*)(a_p + rowbase + tid * 4) = 0;
    else if (tid < 64) *(uint32_t*)(a_p + rowbase + 65 * 128 + (tid - 32) * 4) = 0;
  }
  if (h == 0) {  // zero row h'=0 (quarter per y-block)
    uint32_t* zr = (uint32_t*)(a_p + (size_t)b * HP * ROWB) + (id & 3) * 528;
    for (int k = tid; k < 528; k += 256) zr[k] = 0;
  } else if (h == 63) {  // zero row h'=65
    uint32_t* zr = (uint32_t*)(a_p + ((size_t)b * HP + 65) * ROWB) + (id & 3) * 528;
    for (int k = tid; k < 528; k += 256) zr[k] = 0;
  }
}

// ---------- kernel B: binary conv, MX-fp4, whole-tap batched loads ----------
// Round-26: per tap, issue ALL loads (8 global W b128 + 8 LDS B b128, both kh)
// together, ONE lgkmcnt wait, then one 32-MFMA burst. Halves wait exposures
// 18 -> 9/wave and overlaps global+LDS latencies. Live ~148 regs <= 170 cap.
// Dependent acc reuse (kh0 vs kh1 of same [mi][ni]) is 16 MFMAs apart.
#define LOADW8(dst, t) {                                                          \
  _Pragma("unroll") for (int kh = 0; kh < 2; ++kh)                                \
  _Pragma("unroll") for (int mi = 0; mi < 4; ++mi)                                \
      dst[kh * 4 + mi] = *(const int4v*)(wtb +                                    \
        ((((size_t)(t) * 4 + wv) * 2 + kh) * 4 + mi) * 1024 + l * 16); }

#define LOADB8(dst, d, dxi) {                                                     \
  _Pragma("unroll") for (int kh = 0; kh < 2; ++kh) {                              \
    int ch_ = kh * 4 + lk;                                                        \
    _Pragma("unroll") for (int ni = 0; ni < 4; ++ni) {                            \
      int wp_ = ni * 16 + lm + (dxi);                                             \
      dst[kh * 4 + ni] = *(const int4v*)(smem + (d) * ROWB + wp_ * 128 +          \
                                         (((ch_ ^ wp_) & 7) << 4)); } } }

__global__ __launch_bounds__(256, 3) void bconv(
    const uint8_t* __restrict__ a_p, const uint8_t* __restrict__ wtb,
    const float* __restrict__ scale, const float* __restrict__ x,
    const float* __restrict__ pb0, const float* __restrict__ alpha,
    const float* __restrict__ pb1, float* __restrict__ out) {
  __shared__ __attribute__((aligned(16))) uint8_t smem[STAGEB];
  // XCD-aware bijective swizzle: 1024 blocks, 8 XCDs, 128 contiguous per XCD
  int bh = (blockIdx.x & 7) * 128 + (blockIdx.x >> 3);
  int b = bh >> 6, h = bh & 63;
  int tid = threadIdx.x, l = tid & 63, wv = tid >> 6;
  int lm = l & 15, lk = l >> 4;
  int wm = wv * 64;

  // stage 3 contiguous padded rows (h', h'+1, h'+2) = input rows h-1,h,h+1
  const uint8_t* src = a_p + (size_t)(b * HP + h) * ROWB;
#pragma unroll
  for (int it = 0; it < 6; ++it)
    gl_lds16(src + (size_t)(it * 256 + tid) * 16, smem + it * 4096 + wv * 1024);
  if (tid < 48) gl_lds16(src + 24576 + (size_t)tid * 16, smem + 24576);

  f32x4 acc[4][4];
#pragma unroll
  for (int i = 0; i < 4; ++i)
#pragma unroll
    for (int j = 0; j < 4; ++j) acc[i][j] = (f32x4){0.f, 0.f, 0.f, 0.f};

  asm volatile("s_waitcnt vmcnt(0)" ::: "memory");
  __syncthreads();

  int4v wf[8], bf[8];
#pragma unroll 1
  for (int t = 0; t < 9; ++t) {      // tap loop NOT unrolled: fences code motion
    int d = t / 3, dxi = t - d * 3;
    LOADW8(wf, t)                    // 8 global b128 (L2-resident wtb)
    LOADB8(bf, d, dxi)               // 8 LDS b128 — latencies overlap
    __builtin_amdgcn_s_setprio(1);
#pragma unroll
    for (int kh = 0; kh < 2; ++kh)   // kh-outermost: dep acc pairs 16 apart
#pragma unroll
      for (int mi = 0; mi < 4; ++mi)
#pragma unroll
        for (int ni = 0; ni < 4; ++ni)
          acc[mi][ni] = __builtin_amdgcn_mfma_scale_f32_16x16x128_f8f6f4(
              EXT8(wf[kh * 4 + mi]), EXT8(bf[kh * 4 + ni]), acc[mi][ni],
              4, 4, 0, 127, 0, 127);
    __builtin_amdgcn_s_setprio(0);
  }

  // epilogue: conv*scale + pb0 -> PReLU -> + pb1 + x (residual)
  size_t xb = (size_t)b * C_ * H_ * W_ + (size_t)h * W_;
#pragma unroll
  for (int mi = 0; mi < 4; ++mi) {
#pragma unroll
    for (int j = 0; j < 4; ++j) {
      int o = wm + mi * 16 + lk * 4 + j;  // C/D row = (lane>>4)*4 + reg
      float sc = scale[o], b0 = pb0[o], al = alpha[o], b1 = pb1[o];
      size_t rowo = xb + (size_t)o * (H_ * W_);
#pragma unroll
      for (int ni = 0; ni < 4; ++ni) {
        int wcol = ni * 16 + lm;          // C/D col = lane&15
        float v = acc[mi][ni][j] * sc + b0;
        v = v >= 0.f ? v : al * v;
        v = v + b1 + x[rowo + wcol];
        out[rowo + wcol] = v;
      }
    }
  }
}

extern "C" void kernel_launch(void* const* d_in, const int* in_sizes, int n_in,
                              void* d_out, int out_size, void* d_ws, size_t ws_size,
                              hipStream_t stream) {
  const float* x     = (const float*)d_in[0];
  const float* m0b   = (const float*)d_in[1];
  const float* w     = (const float*)d_in[2];
  const float* pb0   = (const float*)d_in[3];
  const float* alpha = (const float*)d_in[4];
  const float* pb1   = (const float*)d_in[5];
  float* out = (float*)d_out;

  // ws: [0,4KB) scale | [4096, +294912+pad) wtb fp4 | a_p padded 16*66*8448 = 8.9MB
  float* scale = (float*)d_ws;
  uint8_t* wtb = (uint8_t*)d_ws + 4096;
  uint8_t* a_p = (uint8_t*)d_ws + 4096 + (size_t)9 * 4 * 2 * 4 * 1024 + 1024;

  hipLaunchKernelGGL(prep_and_binarize, dim3(256 + B_ * H_ * 4), dim3(256), 0,
                     stream, w, scale, wtb, x, m0b, a_p);
  hipLaunchKernelGGL(bconv, dim3(B_ * H_), dim3(256), 0, stream,
                     a_p, wtb, scale, x, pb0, alpha, pb1, out);
}